// Round 1
// baseline (1150.329 us; speedup 1.0000x reference)
//
#include <hip/hip_runtime.h>

#define BS    128
#define MEM   262144
#define SDIM  512
#define CDIM  313
#define TOPK  256
#define NCHUNK (MEM / 16)   // 16384 chunk maxima per batch row

typedef __attribute__((ext_vector_type(8))) short bf16x8;
typedef __attribute__((ext_vector_type(4))) float floatx4;

// fp32 -> bf16 round-to-nearest-even (no NaN handling needed for this data)
__device__ __forceinline__ unsigned short f2bf(float f) {
    unsigned u = __float_as_uint(f);
    u += 0x7FFFu + ((u >> 16) & 1u);
    return (unsigned short)(u >> 16);
}
// order-preserving map of bf16 bit pattern to ascending uint16
__device__ __forceinline__ unsigned short map16(unsigned short us) {
    return (us & 0x8000u) ? (unsigned short)(~us) : (unsigned short)(us | 0x8000u);
}
__device__ __forceinline__ float unmap16(unsigned m) {
    unsigned short us = (m & 0x8000u) ? (unsigned short)(m ^ 0x8000u) : (unsigned short)(~m);
    return __uint_as_float(((unsigned)us) << 16);
}
__device__ __forceinline__ unsigned map32(float f) {
    unsigned u = __float_as_uint(f);
    return (u & 0x80000000u) ? ~u : (u | 0x80000000u);
}
__device__ __forceinline__ float unmap32(unsigned m) {
    unsigned u = (m & 0x80000000u) ? (m & 0x7FFFFFFFu) : ~m;
    return __uint_as_float(u);
}

// ---------------- K1a: per-row 1/||q|| ----------------
__global__ void k_norm(const float* __restrict__ q, float* __restrict__ rnorm) {
    const int row = blockIdx.x, lane = threadIdx.x;  // 64 threads
    const float* qr = q + row * SDIM;
    float s = 0.f;
    #pragma unroll
    for (int i = 0; i < SDIM / 64; ++i) { float v = qr[lane + i * 64]; s += v * v; }
    #pragma unroll
    for (int o = 32; o; o >>= 1) s += __shfl_xor(s, o);
    if (lane == 0) rnorm[row] = 1.0f / sqrtf(s);
}

// ---------------- K1b: build B-fragment-swizzled normalized q (bf16) ----------------
// layout: [ks(16)][frag(8)][lane(64)][j(8)] ; element = qn[f*16+(lane&15)][ks*32+(lane>>4)*8+j]
__global__ void k_swz(const float* __restrict__ q, const float* __restrict__ rnorm,
                      unsigned short* __restrict__ qswz_g) {
    const int t = blockIdx.x * blockDim.x + threadIdx.x;   // [0, 65536)
    const int ks = t >> 12, f = (t >> 9) & 7, ln = (t >> 3) & 63, j = t & 7;
    const int n = f * 16 + (ln & 15);
    const int k = ks * 32 + (ln >> 4) * 8 + j;
    qswz_g[t] = f2bf(q[n * SDIM + k] * rnorm[n]);
}

// ---------------- K2: scores = keys(bf16) @ q(bf16)^T via MFMA, + chunk maxima ----------------
__global__ __launch_bounds__(1024, 4) void k_gemm(
    const float* __restrict__ key, const uint4* __restrict__ qswz_g,
    unsigned short* __restrict__ scores, unsigned short* __restrict__ cmax) {
    extern __shared__ unsigned short qswz[];   // 131072 B
    {
        uint4* d = (uint4*)qswz;
        for (int i = threadIdx.x; i < 8192; i += 1024) d[i] = qswz_g[i];
    }
    __syncthreads();

    const int lane = threadIdx.x & 63, w = threadIdx.x >> 6;
    const int lm = lane & 15, kg = lane >> 4;
    const long mbase = (long)blockIdx.x * 256 + w * 16;   // this wave's 16 key rows
    const float* kp = key + (mbase + lm) * SDIM + kg * 8;

    floatx4 acc[8];
    #pragma unroll
    for (int f = 0; f < 8; ++f) acc[f] = (floatx4){0.f, 0.f, 0.f, 0.f};

    const bf16x8* qv = (const bf16x8*)qswz;
    float4 a0 = *(const float4*)(kp);
    float4 a1 = *(const float4*)(kp + 4);
    #pragma unroll
    for (int ks = 0; ks < 16; ++ks) {
        float4 b0 = a0, b1 = a1;
        if (ks < 15) {   // one-step lookahead prefetch
            a0 = *(const float4*)(kp + (ks + 1) * 32);
            a1 = *(const float4*)(kp + (ks + 1) * 32 + 4);
        }
        union { bf16x8 v; unsigned short u[8]; } A;
        A.u[0] = f2bf(b0.x); A.u[1] = f2bf(b0.y); A.u[2] = f2bf(b0.z); A.u[3] = f2bf(b0.w);
        A.u[4] = f2bf(b1.x); A.u[5] = f2bf(b1.y); A.u[6] = f2bf(b1.z); A.u[7] = f2bf(b1.w);
        #pragma unroll
        for (int f = 0; f < 8; ++f) {
            bf16x8 b = qv[(ks * 8 + f) * 64 + lane];
            acc[f] = __builtin_amdgcn_mfma_f32_16x16x32_bf16(A.v, b, acc[f], 0, 0, 0);
        }
    }
    // epilogue: bf16 scores + per-16-row chunk maxima (stored pre-mapped)
    #pragma unroll
    for (int f = 0; f < 8; ++f) {
        const int n = f * 16 + lm;                    // batch column
        unsigned short s0 = f2bf(acc[f][0]), s1 = f2bf(acc[f][1]),
                       s2 = f2bf(acc[f][2]), s3 = f2bf(acc[f][3]);
        ushort4 pk; pk.x = s0; pk.y = s1; pk.z = s2; pk.w = s3;
        *(ushort4*)(scores + (size_t)n * MEM + mbase + kg * 4) = pk;  // rows kg*4..kg*4+3
        int mv = max(max((int)map16(s0), (int)map16(s1)), max((int)map16(s2), (int)map16(s3)));
        mv = max(mv, __shfl_xor(mv, 16));
        mv = max(mv, __shfl_xor(mv, 32));
        if (kg == 0) cmax[(size_t)n * NCHUNK + (mbase >> 4)] = (unsigned short)mv;
    }
}

// ---------------- K3: exact top-256 set per row, KL gating, hinge, mean ----------------
__global__ __launch_bounds__(1024) void k_final(
    const unsigned short* __restrict__ scores, const unsigned short* __restrict__ cmax,
    const float* __restrict__ cfeat, const float* __restrict__ cvalue,
    float* __restrict__ out) {
    __shared__ unsigned short s_cm[NCHUNK];   // 32 KB, pre-mapped chunk maxima
    __shared__ unsigned short s_vals[8192];   // 16 KB, mapped candidate scores
    __shared__ int s_cand[512];
    __shared__ float s_lb[CDIM];
    __shared__ int s_part[16];
    __shared__ int s_total;
    __shared__ int s_n;
    __shared__ unsigned s_pm, s_nm;
    const int tid = threadIdx.x, lane = tid & 63, wid = tid >> 6;
    const int row = blockIdx.x;

    for (int i = tid; i < NCHUNK; i += 1024) s_cm[i] = cmax[(size_t)row * NCHUNK + i];
    for (int c = tid; c < CDIM; c += 1024) s_lb[c] = __log2f(cfeat[row * CDIM + c] + 1e-8f);
    if (tid == 0) { s_n = 0; s_pm = 0u; s_nm = 0u; }
    __syncthreads();

    // tau = rank-256 value over chunk maxima (bitwise binary search, 16 bits)
    int tau = 0;
    for (int b = 15; b >= 0; --b) {
        const int cand = tau | (1 << b);
        int cnt = 0;
        for (int i = tid; i < NCHUNK; i += 1024) cnt += ((int)s_cm[i] >= cand);
        #pragma unroll
        for (int o = 32; o; o >>= 1) cnt += __shfl_xor(cnt, o);
        if (lane == 0) s_part[wid] = cnt;
        __syncthreads();
        if (tid == 0) { int t2 = 0; for (int k = 0; k < 16; ++k) t2 += s_part[k]; s_total = t2; }
        __syncthreads();
        if (s_total >= TOPK) tau = cand;
        __syncthreads();
    }
    // candidate chunks (count == rank ties included; ~256 for real data)
    for (int c = tid; c < NCHUNK; c += 1024)
        if ((int)s_cm[c] >= tau) { int p = atomicAdd(&s_n, 1); if (p < 512) s_cand[p] = c; }
    __syncthreads();
    const int ncand = min(s_n, 512);
    const int nval = ncand * 16;
    const unsigned short* srow = scores + (size_t)row * MEM;
    for (int s = tid; s < nval; s += 1024)
        s_vals[s] = map16(srow[s_cand[s >> 4] * 16 + (s & 15)]);
    __syncthreads();

    // t = rank-256 value over candidate scores -> exact top-256 set (ties included)
    int tv = 0;
    for (int b = 15; b >= 0; --b) {
        const int cand = tv | (1 << b);
        int cnt = 0;
        for (int s = tid; s < nval; s += 1024) cnt += ((int)s_vals[s] >= cand);
        #pragma unroll
        for (int o = 32; o; o >>= 1) cnt += __shfl_xor(cnt, o);
        if (lane == 0) s_part[wid] = cnt;
        __syncthreads();
        if (tid == 0) { int t2 = 0; for (int k = 0; k < 16; ++k) t2 += s_part[k]; s_total = t2; }
        __syncthreads();
        if (s_total >= TOPK) tv = cand;
        __syncthreads();
    }

    // KL per selected element; each set element contributes (mask?val:0) to pos
    // and (mask?0:val) to neg -- matches max(score*mask) semantics exactly.
    float pmax = 0.f, nmax = 0.f;
    bool any = false;
    for (int s = tid; s < nval; s += 1024) {
        if ((int)s_vals[s] >= tv) {
            const int m = s_cand[s >> 4] * 16 + (s & 15);
            const float val = unmap16(s_vals[s]);
            const float* a = cvalue + (size_t)m * CDIM;
            float kl = 0.f;
            #pragma unroll 4
            for (int c = 0; c < CDIM; ++c) {
                float av = a[c];
                kl += av * (__log2f(av) - s_lb[c]);
            }
            kl *= 0.30102999566398f;   // log10(x) = log2(x) * log10(2)
            const bool mask = kl < 0.005f;
            const float p = mask ? val : 0.f;
            const float q2 = mask ? 0.f : val;
            if (!any) { pmax = p; nmax = q2; any = true; }
            else { pmax = fmaxf(pmax, p); nmax = fmaxf(nmax, q2); }
        }
    }
    if (any) { atomicMax(&s_pm, map32(pmax)); atomicMax(&s_nm, map32(nmax)); }
    __syncthreads();
    if (tid == 0) {
        const float pos = unmap32(s_pm), neg = unmap32(s_nm);
        const float loss = fmaxf(neg - pos + 0.1f, 0.f);
        atomicAdd(out, loss * (1.0f / (float)BS));
    }
}

extern "C" void kernel_launch(void* const* d_in, const int* in_sizes, int n_in,
                              void* d_out, int out_size, void* d_ws, size_t ws_size,
                              hipStream_t stream) {
    const float* query  = (const float*)d_in[0];   // [128][512]
    const float* cfeat  = (const float*)d_in[1];   // [128][313]
    const float* skey   = (const float*)d_in[2];   // [262144][512]
    const float* cvalue = (const float*)d_in[3];   // [262144][313]
    float* out = (float*)d_out;

    char* ws = (char*)d_ws;
    unsigned short* qswz_g = (unsigned short*)ws;                        // 131072 B
    float* rnorm = (float*)(ws + 131072);                                // 512 B
    unsigned short* scores = (unsigned short*)(ws + 262144);             // 67,108,864 B
    unsigned short* cmaxb  = (unsigned short*)(ws + 262144 + 67108864);  // 4,194,304 B
    // total ws use: 71,565,312 B

    hipMemsetAsync(d_out, 0, sizeof(float), stream);
    k_norm<<<BS, 64, 0, stream>>>(query, rnorm);
    k_swz<<<64, 1024, 0, stream>>>(query, rnorm, qswz_g);
    hipFuncSetAttribute(reinterpret_cast<const void*>(k_gemm),
                        hipFuncAttributeMaxDynamicSharedMemorySize, 131072);
    k_gemm<<<MEM / 256, 1024, 131072, stream>>>(skey, (const uint4*)qswz_g, scores, cmaxb);
    k_final<<<BS, 1024, 0, stream>>>(scores, cmaxb, cfeat, cvalue, out);
}